// Round 1
// baseline (560.440 us; speedup 1.0000x reference)
//
#include <hip/hip_runtime.h>
#include <hip/hip_bf16.h>

typedef unsigned short u16;
typedef unsigned int   u32;
typedef __attribute__((ext_vector_type(8))) __bf16 bf16x8;
typedef __attribute__((ext_vector_type(4))) float  f32x4;
typedef __attribute__((ext_vector_type(8))) u16    u16x8;
typedef __attribute__((ext_vector_type(4))) u16    u16x4;

#define S_LEN 2048
#define DMODEL 4096
#define NH 64
#define NKV 4
#define HD 64

__device__ __forceinline__ u16 f2bf(float f) {
  u32 u = __builtin_bit_cast(u32, f);
  u32 r = (u + 0x7FFFu + ((u >> 16) & 1u)) >> 16;
  return (u16)r;
}

__device__ __forceinline__ void gll16(const void* g, void* l) {
  __builtin_amdgcn_global_load_lds(
      (__attribute__((address_space(1))) void*)g,
      (__attribute__((address_space(3))) void*)l, 16, 0, 0);
}

// ---------------- elementwise converts ----------------
__global__ __launch_bounds__(256) void cvt_f32_bf16_v4(const float* __restrict__ in,
                                                       u16* __restrict__ out) {
  const int i = blockIdx.x * 256 + threadIdx.x;
  float4 f = ((const float4*)in)[i];
  u16x4 u = { f2bf(f.x), f2bf(f.y), f2bf(f.z), f2bf(f.w) };
  *(u16x4*)&out[(size_t)i * 4] = u;
}

// extract V half of KV fp32 buffer -> bf16
__global__ __launch_bounds__(256) void cvt_v(const float* __restrict__ kvf,
                                             u16* __restrict__ vb) {
  const int i = blockIdx.x * 256 + threadIdx.x;   // over S_LEN*64 float4 groups
  const int s = i >> 6, c = (i & 63) << 2;
  float4 f = *(const float4*)&kvf[(size_t)s * 512 + 256 + c];
  u16x4 u = { f2bf(f.x), f2bf(f.y), f2bf(f.z), f2bf(f.w) };
  *(u16x4*)&vb[(size_t)s * 256 + c] = u;
}

// transpose-convert: in fp32 R x C row-major -> out bf16 C x R row-major
__global__ __launch_bounds__(256) void tconv(const float* __restrict__ in,
                                             u16* __restrict__ out, int R, int C) {
  __shared__ float tile[32][33];
  const int nc = C >> 5;
  const int cb = blockIdx.x % nc, rb = blockIdx.x / nc;
  const int tx = threadIdx.x & 31, ty = threadIdx.x >> 5;
#pragma unroll
  for (int i = 0; i < 4; ++i)
    tile[ty + i * 8][tx] = in[(size_t)(rb * 32 + ty + i * 8) * C + cb * 32 + tx];
  __syncthreads();
#pragma unroll
  for (int i = 0; i < 4; ++i)
    out[(size_t)(cb * 32 + ty + i * 8) * R + rb * 32 + tx] = f2bf(tile[tx][ty + i * 8]);
}

// ---------------- RMSNorm + RoPE (one wave = one (s,head) row of 64) ------------
__global__ __launch_bounds__(256) void norm_rope(const float* __restrict__ in, int in_stride,
                                                 int nheads,
                                                 const float* __restrict__ nw,
                                                 const float* __restrict__ cosT,
                                                 const float* __restrict__ sinT,
                                                 u16* __restrict__ outp, int out_stride) {
  const int wid = blockIdx.x * 4 + (threadIdx.x >> 6);
  const int l = threadIdx.x & 63;
  const int s = wid / nheads, h = wid - s * nheads;
  const float v = in[(size_t)s * in_stride + h * 64 + l];
  float sq = v * v;
#pragma unroll
  for (int off = 32; off; off >>= 1) sq += __shfl_xor(sq, off, 64);
  const float rr = rsqrtf(sq * (1.f / 64.f) + 1e-5f);
  const float vn = v * rr * nw[l];
  const float p = __shfl_xor(vn, 1, 64);
  const int i2 = l >> 1;
  const float c = cosT[(size_t)s * 32 + i2];
  const float sn = sinT[(size_t)s * 32 + i2];
  const float o = (l & 1) ? fmaf(p, sn, vn * c) : fmaf(-p, sn, vn * c);
  outp[(size_t)s * out_stride + h * 64 + l] = f2bf(o);
}

// ---------------- GEMM: C(MxN fp32) = A(MxK bf16 rowmajor) @ Bt(NxK bf16 rowmajor)^T
__global__ __launch_bounds__(256) void gemm_bt(const u16* __restrict__ A,
                                               const u16* __restrict__ Bt,
                                               float* __restrict__ C,
                                               int M, int N, int K) {
  __shared__ __align__(16) u16 As[128 * 32];
  __shared__ __align__(16) u16 Bs[128 * 32];
  const int nbn = N >> 7;
  const int bm = blockIdx.x / nbn, bn = blockIdx.x % nbn;
  const int m0 = bm << 7, n0 = bn << 7;
  const int tid = threadIdx.x;
  const int w = tid >> 6, l = tid & 63;
  const int wr = w >> 1, wc = w & 1;
  f32x4 acc[4][4] = {};

  const char* Ag = (const char*)A + ((size_t)(m0 + w * 32 + (l >> 2)) * K + (l & 3) * 8) * 2;
  const char* Bg = (const char*)Bt + ((size_t)(n0 + w * 32 + (l >> 2)) * K + (l & 3) * 8) * 2;
  char* Al = (char*)As + (w * 32) * 64;
  char* Bl = (char*)Bs + (w * 32) * 64;
  const size_t rowadv = (size_t)16 * K * 2;

  for (int k0 = 0; k0 < K; k0 += 32) {
    gll16(Ag, Al);
    gll16(Ag + rowadv, Al + 1024);
    gll16(Bg, Bl);
    gll16(Bg + rowadv, Bl + 1024);
    Ag += 64; Bg += 64;
    __syncthreads();
    bf16x8 af[4], bq[4];
#pragma unroll
    for (int i = 0; i < 4; ++i) {
      af[i] = *(const bf16x8*)&As[(wr * 64 + i * 16 + (l & 15)) * 32 + (l >> 4) * 8];
      bq[i] = *(const bf16x8*)&Bs[(wc * 64 + i * 16 + (l & 15)) * 32 + (l >> 4) * 8];
    }
#pragma unroll
    for (int mi = 0; mi < 4; ++mi)
#pragma unroll
      for (int ni = 0; ni < 4; ++ni)
        acc[mi][ni] = __builtin_amdgcn_mfma_f32_16x16x32_bf16(af[mi], bq[ni], acc[mi][ni], 0, 0, 0);
    __syncthreads();
  }
  const int r0 = (l >> 4) * 4, c0 = l & 15;
#pragma unroll
  for (int mi = 0; mi < 4; ++mi)
#pragma unroll
    for (int ni = 0; ni < 4; ++ni)
#pragma unroll
      for (int r = 0; r < 4; ++r)
        C[(size_t)(m0 + wr * 64 + mi * 16 + r0 + r) * N + (n0 + wc * 64 + ni * 16 + c0)] =
            acc[mi][ni][r];
}

// ---------------- flash attention (causal, GQA) ----------------
// grid: (S/64) * NH blocks, 256 threads. block -> qb = bid>>6, h = bid&63.
__global__ __launch_bounds__(256) void attn_fwd(const u16* __restrict__ Q,
                                                const u16* __restrict__ Kb,
                                                const u16* __restrict__ Vb,
                                                u16* __restrict__ O) {
  const int h = blockIdx.x & 63;
  const int qb = blockIdx.x >> 6;
  const int kvh = h >> 4;
  __shared__ __align__(16) u16 Ks[64 * 64];
  __shared__ __align__(16) u16 Vt[64 * 64];
  __shared__ __align__(16) u16 Ps[4][16 * 64];
  const int tid = threadIdx.x;
  const int w = tid >> 6, l = tid & 63;
  const int lr = l & 15, lg = l >> 4;

  bf16x8 qf[2];
  {
    const size_t qoff = (size_t)(qb * 64 + w * 16 + lr) * DMODEL + h * HD + lg * 8;
    qf[0] = *(const bf16x8*)&Q[qoff];
    qf[1] = *(const bf16x8*)&Q[qoff + 32];
  }
  f32x4 o[4] = {};
  float mrow[4] = {-1e30f, -1e30f, -1e30f, -1e30f};
  float lrow[4] = {0.f, 0.f, 0.f, 0.f};

  const int vkv = tid >> 2, vd0 = (tid & 3) << 4;
  const int ntiles = qb + 1;

  for (int t = 0; t < ntiles; ++t) {
    const int kv0 = t * 64;
    __syncthreads();
    // stage K tile (64 rows x 128B) via global_load_lds
    {
      const char* kg = (const char*)Kb +
          ((size_t)(kv0 + w * 16 + (l >> 3)) * (NKV * HD) + kvh * HD) * 2 + (l & 7) * 16;
      char* kl = (char*)Ks + w * 16 * 128;
      gll16(kg, kl);
      gll16(kg + (size_t)8 * (NKV * HD) * 2, kl + 1024);
    }
    // stage V transposed: Vt[d][kv]
    {
      const size_t vo = (size_t)(kv0 + vkv) * (NKV * HD) + kvh * HD + vd0;
      u16x8 v0 = *(const u16x8*)&Vb[vo];
      u16x8 v1 = *(const u16x8*)&Vb[vo + 8];
#pragma unroll
      for (int j = 0; j < 8; ++j) Vt[(vd0 + j) * 64 + vkv] = v0[j];
#pragma unroll
      for (int j = 0; j < 8; ++j) Vt[(vd0 + 8 + j) * 64 + vkv] = v1[j];
    }
    __syncthreads();

    // S = Q @ K^T
    f32x4 sf[4] = {};
#pragma unroll
    for (int ni = 0; ni < 4; ++ni) {
      bf16x8 kf0 = *(const bf16x8*)&Ks[(ni * 16 + lr) * 64 + (lg * 8)];
      bf16x8 kf1 = *(const bf16x8*)&Ks[(ni * 16 + lr) * 64 + 32 + (lg * 8)];
      sf[ni] = __builtin_amdgcn_mfma_f32_16x16x32_bf16(qf[0], kf0, sf[ni], 0, 0, 0);
      sf[ni] = __builtin_amdgcn_mfma_f32_16x16x32_bf16(qf[1], kf1, sf[ni], 0, 0, 0);
    }
    // scale + causal mask + online softmax
    const int qrow0 = qb * 64 + w * 16 + lg * 4;
    float mx[4] = {-1e30f, -1e30f, -1e30f, -1e30f};
#pragma unroll
    for (int ni = 0; ni < 4; ++ni) {
      const int col = kv0 + ni * 16 + lr;
#pragma unroll
      for (int r = 0; r < 4; ++r) {
        float s = sf[ni][r] * 0.125f;
        if (col > qrow0 + r) s = -1e30f;
        sf[ni][r] = s;
        mx[r] = fmaxf(mx[r], s);
      }
    }
#pragma unroll
    for (int r = 0; r < 4; ++r) {
#pragma unroll
      for (int off = 1; off < 16; off <<= 1)
        mx[r] = fmaxf(mx[r], __shfl_xor(mx[r], off, 64));
    }
    float alpha[4], rs[4];
#pragma unroll
    for (int r = 0; r < 4; ++r) {
      float mn = fmaxf(mrow[r], mx[r]);
      alpha[r] = __expf(mrow[r] - mn);
      mrow[r] = mn;
      rs[r] = 0.f;
    }
#pragma unroll
    for (int ni = 0; ni < 4; ++ni)
#pragma unroll
      for (int r = 0; r < 4; ++r) {
        float p = __expf(sf[ni][r] - mrow[r]);
        sf[ni][r] = p;
        rs[r] += p;
      }
#pragma unroll
    for (int r = 0; r < 4; ++r) {
#pragma unroll
      for (int off = 1; off < 16; off <<= 1)
        rs[r] += __shfl_xor(rs[r], off, 64);
      lrow[r] = lrow[r] * alpha[r] + rs[r];
      o[0][r] *= alpha[r];
      o[1][r] *= alpha[r];
      o[2][r] *= alpha[r];
      o[3][r] *= alpha[r];
    }
    // P (C-layout) -> LDS -> A-layout
#pragma unroll
    for (int ni = 0; ni < 4; ++ni)
#pragma unroll
      for (int r = 0; r < 4; ++r)
        Ps[w][(lg * 4 + r) * 64 + ni * 16 + lr] = f2bf(sf[ni][r]);
    // O += P @ V
#pragma unroll
    for (int kk = 0; kk < 2; ++kk) {
      bf16x8 pa = *(const bf16x8*)&Ps[w][lr * 64 + kk * 32 + lg * 8];
#pragma unroll
      for (int ni = 0; ni < 4; ++ni) {
        bf16x8 vf = *(const bf16x8*)&Vt[(ni * 16 + lr) * 64 + kk * 32 + lg * 8];
        o[ni] = __builtin_amdgcn_mfma_f32_16x16x32_bf16(pa, vf, o[ni], 0, 0, 0);
      }
    }
  }
#pragma unroll
  for (int ni = 0; ni < 4; ++ni)
#pragma unroll
    for (int r = 0; r < 4; ++r) {
      const size_t orow = (size_t)(qb * 64 + w * 16 + lg * 4 + r);
      O[orow * DMODEL + h * HD + ni * 16 + lr] = f2bf(o[ni][r] / lrow[r]);
    }
}

// ---------------- launcher ----------------
extern "C" void kernel_launch(void* const* d_in, const int* in_sizes, int n_in,
                              void* d_out, int out_size, void* d_ws, size_t ws_size,
                              hipStream_t stream) {
  const float* x   = (const float*)d_in[0];
  const float* wq  = (const float*)d_in[1];
  const float* wk  = (const float*)d_in[2];
  const float* wv  = (const float*)d_in[3];
  const float* wo  = (const float*)d_in[4];
  const float* qnw = (const float*)d_in[5];
  const float* knw = (const float*)d_in[6];
  const float* fc  = (const float*)d_in[7];
  const float* fs  = (const float*)d_in[8];
  float* out = (float*)d_out;

  char* ws = (char*)d_ws;
  size_t off = 0;
  auto alloc = [&](size_t bytes) {
    char* p = ws + off;
    off += (bytes + 255) & ~(size_t)255;
    return p;
  };
  u16*   xb   = (u16*)alloc((size_t)S_LEN * DMODEL * 2);
  u16*   wqT  = (u16*)alloc((size_t)DMODEL * DMODEL * 2);
  u16*   wkvT = (u16*)alloc((size_t)512 * DMODEL * 2);
  u16*   woT  = (u16*)alloc((size_t)DMODEL * DMODEL * 2);
  float* KVf  = (float*)alloc((size_t)S_LEN * 512 * 4);
  u16*   Qn   = (u16*)alloc((size_t)S_LEN * DMODEL * 2);
  u16*   Kn   = (u16*)alloc((size_t)S_LEN * 256 * 2);
  u16*   Vbf  = (u16*)alloc((size_t)S_LEN * 256 * 2);
  u16*   Ob   = (u16*)alloc((size_t)S_LEN * DMODEL * 2);
  float* Qf   = out;  // reuse d_out as fp32 Q scratch (fully overwritten at the end)

  cvt_f32_bf16_v4<<<(S_LEN * DMODEL / 4) / 256, 256, 0, stream>>>(x, xb);
  tconv<<<(4096 / 32) * (4096 / 32), 256, 0, stream>>>(wq, wqT, 4096, 4096);
  tconv<<<(4096 / 32) * (256 / 32), 256, 0, stream>>>(wk, wkvT, 4096, 256);
  tconv<<<(4096 / 32) * (256 / 32), 256, 0, stream>>>(wv, wkvT + (size_t)256 * 4096, 4096, 256);
  tconv<<<(4096 / 32) * (4096 / 32), 256, 0, stream>>>(wo, woT, 4096, 4096);

  gemm_bt<<<(2048 / 128) * (4096 / 128), 256, 0, stream>>>(xb, wqT, Qf, 2048, 4096, 4096);
  gemm_bt<<<(2048 / 128) * (512 / 128), 256, 0, stream>>>(xb, wkvT, KVf, 2048, 512, 4096);

  norm_rope<<<(S_LEN * NH) / 4, 256, 0, stream>>>(Qf, DMODEL, NH, qnw, fc, fs, Qn, DMODEL);
  norm_rope<<<(S_LEN * NKV) / 4, 256, 0, stream>>>(KVf, 512, NKV, knw, fc, fs, Kn, 256);
  cvt_v<<<(S_LEN * 64) / 256, 256, 0, stream>>>(KVf, Vbf);

  attn_fwd<<<(S_LEN / 64) * NH, 256, 0, stream>>>(Qn, Kn, Vbf, Ob);

  gemm_bt<<<(2048 / 128) * (4096 / 128), 256, 0, stream>>>(Ob, woT, out, 2048, 4096, 4096);
}

// Round 2
// 479.910 us; speedup vs baseline: 1.1678x; 1.1678x over previous
//
#include <hip/hip_runtime.h>
#include <hip/hip_bf16.h>

typedef unsigned short u16;
typedef unsigned int   u32;
typedef __attribute__((ext_vector_type(8))) __bf16 bf16x8;
typedef __attribute__((ext_vector_type(4))) float  f32x4;
typedef __attribute__((ext_vector_type(8))) u16    u16x8;
typedef __attribute__((ext_vector_type(4))) u16    u16x4;

#define S_LEN 2048
#define DMODEL 4096
#define NH 64
#define NKV 4
#define HD 64

__device__ __forceinline__ u16 f2bf(float f) {
  u32 u = __builtin_bit_cast(u32, f);
  u32 r = (u + 0x7FFFu + ((u >> 16) & 1u)) >> 16;
  return (u16)r;
}

__device__ __forceinline__ void gll16(const void* g, void* l) {
  __builtin_amdgcn_global_load_lds(
      (__attribute__((address_space(1))) void*)g,
      (__attribute__((address_space(3))) void*)l, 16, 0, 0);
}

// swizzled byte offset within a [rows][8 chunks of 16B] tile (128B row stride)
#define SWZ(row, chunk) (((row) * 128) + ((((chunk) ^ ((row) & 7))) << 4))

// ---------------- elementwise converts ----------------
__global__ __launch_bounds__(256) void cvt_f32_bf16_v4(const float* __restrict__ in,
                                                       u16* __restrict__ out) {
  const int i = blockIdx.x * 256 + threadIdx.x;
  float4 f = ((const float4*)in)[i];
  u16x4 u = { f2bf(f.x), f2bf(f.y), f2bf(f.z), f2bf(f.w) };
  *(u16x4*)&out[(size_t)i * 4] = u;
}

// transpose-convert with row stride: in fp32 R x C (row stride istride) -> out bf16 C x R
__global__ __launch_bounds__(256) void tconvs(const float* __restrict__ in, int istride,
                                              u16* __restrict__ out, int R, int C) {
  __shared__ float tile[32][33];
  const int nc = C >> 5;
  const int cb = blockIdx.x % nc, rb = blockIdx.x / nc;
  const int tx = threadIdx.x & 31, ty = threadIdx.x >> 5;
#pragma unroll
  for (int i = 0; i < 4; ++i)
    tile[ty + i * 8][tx] = in[(size_t)(rb * 32 + ty + i * 8) * istride + cb * 32 + tx];
  __syncthreads();
#pragma unroll
  for (int i = 0; i < 4; ++i)
    out[(size_t)(cb * 32 + ty + i * 8) * R + rb * 32 + tx] = f2bf(tile[tx][ty + i * 8]);
}

// ---------------- RMSNorm + RoPE (one wave = one (s,head) row of 64) ------------
__global__ __launch_bounds__(256) void norm_rope(const float* __restrict__ in, int in_stride,
                                                 int nheads,
                                                 const float* __restrict__ nw,
                                                 const float* __restrict__ cosT,
                                                 const float* __restrict__ sinT,
                                                 u16* __restrict__ outp, int out_stride) {
  const int wid = blockIdx.x * 4 + (threadIdx.x >> 6);
  const int l = threadIdx.x & 63;
  const int s = wid / nheads, h = wid - s * nheads;
  const float v = in[(size_t)s * in_stride + h * 64 + l];
  float sq = v * v;
#pragma unroll
  for (int off = 32; off; off >>= 1) sq += __shfl_xor(sq, off, 64);
  const float rr = rsqrtf(sq * (1.f / 64.f) + 1e-5f);
  const float vn = v * rr * nw[l];
  const float p = __shfl_xor(vn, 1, 64);
  const int i2 = l >> 1;
  const float c = cosT[(size_t)s * 32 + i2];
  const float sn = sinT[(size_t)s * 32 + i2];
  const float o = (l & 1) ? fmaf(p, sn, vn * c) : fmaf(-p, sn, vn * c);
  outp[(size_t)s * out_stride + h * 64 + l] = f2bf(o);
}

// ---------------- GEMM: C(MxN fp32) = A(MxK bf16 rowmajor) @ Bt(NxK bf16 rowmajor)^T
__global__ __launch_bounds__(256) void gemm_bt(const u16* __restrict__ A,
                                               const u16* __restrict__ Bt,
                                               float* __restrict__ C,
                                               int M, int N, int K) {
  __shared__ __align__(16) u16 As[128 * 32];
  __shared__ __align__(16) u16 Bs[128 * 32];
  // XCD-aware bijective swizzle (all launches have gridDim % 8 == 0)
  int bid = blockIdx.x;
  const int cpx = gridDim.x >> 3;
  bid = (bid & 7) * cpx + (bid >> 3);
  const int nbn = N >> 7;
  const int bm = bid / nbn, bn = bid % nbn;
  const int m0 = bm << 7, n0 = bn << 7;
  const int tid = threadIdx.x;
  const int w = tid >> 6, l = tid & 63;
  const int wr = w >> 1, wc = w & 1;
  f32x4 acc[4][4] = {};

  const char* Ag = (const char*)A + ((size_t)(m0 + w * 32 + (l >> 2)) * K + (l & 3) * 8) * 2;
  const char* Bg = (const char*)Bt + ((size_t)(n0 + w * 32 + (l >> 2)) * K + (l & 3) * 8) * 2;
  char* Al = (char*)As + (w * 32) * 64;
  char* Bl = (char*)Bs + (w * 32) * 64;
  const size_t rowadv = (size_t)16 * K * 2;

  for (int k0 = 0; k0 < K; k0 += 32) {
    gll16(Ag, Al);
    gll16(Ag + rowadv, Al + 1024);
    gll16(Bg, Bl);
    gll16(Bg + rowadv, Bl + 1024);
    Ag += 64; Bg += 64;
    __syncthreads();
    bf16x8 af[4], bq[4];
#pragma unroll
    for (int i = 0; i < 4; ++i) {
      af[i] = *(const bf16x8*)&As[(wr * 64 + i * 16 + (l & 15)) * 32 + (l >> 4) * 8];
      bq[i] = *(const bf16x8*)&Bs[(wc * 64 + i * 16 + (l & 15)) * 32 + (l >> 4) * 8];
    }
#pragma unroll
    for (int mi = 0; mi < 4; ++mi)
#pragma unroll
      for (int ni = 0; ni < 4; ++ni)
        acc[mi][ni] = __builtin_amdgcn_mfma_f32_16x16x32_bf16(af[mi], bq[ni], acc[mi][ni], 0, 0, 0);
    __syncthreads();
  }
  const int r0 = (l >> 4) * 4, c0 = l & 15;
#pragma unroll
  for (int mi = 0; mi < 4; ++mi)
#pragma unroll
    for (int ni = 0; ni < 4; ++ni)
#pragma unroll
      for (int r = 0; r < 4; ++r)
        C[(size_t)(m0 + wr * 64 + mi * 16 + r0 + r) * N + (n0 + wc * 64 + ni * 16 + c0)] =
            acc[mi][ni][r];
}

// ---------------- flash attention (causal, GQA) ----------------
// grid: (S/64) * NH blocks, 256 threads. block -> qb (reversed), h = bid&63.
// K staged [kv][d] swizzled; V staged from pre-transposed VT[d_global][s] swizzled.
__global__ __launch_bounds__(256) void attn_fwd(const u16* __restrict__ Q,
                                                const u16* __restrict__ Kb,
                                                const u16* __restrict__ VT,
                                                u16* __restrict__ O) {
  const int h = blockIdx.x & 63;
  const int qb = (S_LEN / 64 - 1) - (blockIdx.x >> 6);  // big blocks first
  const int kvh = h >> 4;
  __shared__ __align__(16) u16 Ks[64 * 64];
  __shared__ __align__(16) u16 Vs[64 * 64];
  __shared__ __align__(16) u16 Ps[4 * 16 * 64];
  const int tid = threadIdx.x;
  const int w = tid >> 6, l = tid & 63;
  const int lr = l & 15, lg = l >> 4;

  // staging geometry: each wave stages its 16 rows via 2 gll16 (8 rows each).
  const int srow = w * 16 + (l >> 3);       // rows srow and srow+8
  const int slot = l & 7;
  const int sc = slot ^ (srow & 7);         // inverse-swizzled source chunk
  const char* Kg = (const char*)Kb + kvh * 128 + (size_t)srow * 512 + sc * 16;
  const char* Vg = (const char*)VT + (size_t)(kvh * 64 + srow) * (S_LEN * 2) + sc * 16;
  char* Kl = (char*)Ks + w * 2048;
  char* Vl = (char*)Vs + w * 2048;

  bf16x8 qf[2];
  {
    const size_t qoff = (size_t)(qb * 64 + w * 16 + lr) * DMODEL + h * HD + lg * 8;
    qf[0] = *(const bf16x8*)&Q[qoff];
    qf[1] = *(const bf16x8*)&Q[qoff + 32];
  }
  f32x4 o[4] = {};
  float mrow[4] = {-1e30f, -1e30f, -1e30f, -1e30f};
  float lrow[4] = {0.f, 0.f, 0.f, 0.f};
  const int qrow0 = qb * 64 + w * 16 + lg * 4;

  for (int t = 0; t <= qb; ++t) {
    const int kv0 = t * 64;
    __syncthreads();
    gll16(Kg, Kl);
    gll16(Kg + 8 * 512, Kl + 1024);
    gll16(Vg, Vl);
    gll16(Vg + 8 * (S_LEN * 2), Vl + 1024);
    Kg += 64 * 512;
    Vg += 128;
    __syncthreads();

    // S = Q @ K^T  (swizzled K reads)
    f32x4 sf[4] = {};
#pragma unroll
    for (int ni = 0; ni < 4; ++ni) {
      const int row = ni * 16 + lr;
      bf16x8 kf0 = *(const bf16x8*)((const char*)Ks + SWZ(row, lg));
      bf16x8 kf1 = *(const bf16x8*)((const char*)Ks + SWZ(row, 4 + lg));
      sf[ni] = __builtin_amdgcn_mfma_f32_16x16x32_bf16(qf[0], kf0, sf[ni], 0, 0, 0);
      sf[ni] = __builtin_amdgcn_mfma_f32_16x16x32_bf16(qf[1], kf1, sf[ni], 0, 0, 0);
    }
    // scale (+ causal mask only on diagonal tile) + online softmax
    float mx[4] = {-1e30f, -1e30f, -1e30f, -1e30f};
    if (t == qb) {
#pragma unroll
      for (int ni = 0; ni < 4; ++ni) {
        const int col = kv0 + ni * 16 + lr;
#pragma unroll
        for (int r = 0; r < 4; ++r) {
          float s = sf[ni][r] * 0.125f;
          if (col > qrow0 + r) s = -1e30f;
          sf[ni][r] = s;
          mx[r] = fmaxf(mx[r], s);
        }
      }
    } else {
#pragma unroll
      for (int ni = 0; ni < 4; ++ni)
#pragma unroll
        for (int r = 0; r < 4; ++r) {
          float s = sf[ni][r] * 0.125f;
          sf[ni][r] = s;
          mx[r] = fmaxf(mx[r], s);
        }
    }
#pragma unroll
    for (int r = 0; r < 4; ++r) {
#pragma unroll
      for (int off = 1; off < 16; off <<= 1)
        mx[r] = fmaxf(mx[r], __shfl_xor(mx[r], off, 64));
    }
    float alpha[4], rs[4];
#pragma unroll
    for (int r = 0; r < 4; ++r) {
      float mn = fmaxf(mrow[r], mx[r]);
      alpha[r] = __expf(mrow[r] - mn);
      mrow[r] = mn;
      rs[r] = 0.f;
    }
#pragma unroll
    for (int ni = 0; ni < 4; ++ni)
#pragma unroll
      for (int r = 0; r < 4; ++r) {
        float p = __expf(sf[ni][r] - mrow[r]);
        sf[ni][r] = p;
        rs[r] += p;
      }
#pragma unroll
    for (int r = 0; r < 4; ++r) {
#pragma unroll
      for (int off = 1; off < 16; off <<= 1)
        rs[r] += __shfl_xor(rs[r], off, 64);
      lrow[r] = lrow[r] * alpha[r] + rs[r];
      o[0][r] *= alpha[r];
      o[1][r] *= alpha[r];
      o[2][r] *= alpha[r];
      o[3][r] *= alpha[r];
    }
    // P (C-layout) -> LDS, chunk-swizzled
    {
      char* Pw = (char*)Ps + w * 2048;
#pragma unroll
      for (int ni = 0; ni < 4; ++ni) {
        const int kvc = ni * 16 + lr;
        const int chnk = kvc >> 3;
        const int sub = (lr & 7) << 1;
#pragma unroll
        for (int r = 0; r < 4; ++r) {
          const int row = lg * 4 + r;
          *(u16*)(Pw + row * 128 + (((chnk ^ (row & 7))) << 4) + sub) = f2bf(sf[ni][r]);
        }
      }
    }
    // O += P @ V  (swizzled P and V reads)
#pragma unroll
    for (int kk = 0; kk < 2; ++kk) {
      bf16x8 pa = *(const bf16x8*)((const char*)Ps + w * 2048 + SWZ(lr, kk * 4 + lg));
#pragma unroll
      for (int ni = 0; ni < 4; ++ni) {
        const int row = ni * 16 + lr;
        bf16x8 vf = *(const bf16x8*)((const char*)Vs + SWZ(row, kk * 4 + lg));
        o[ni] = __builtin_amdgcn_mfma_f32_16x16x32_bf16(pa, vf, o[ni], 0, 0, 0);
      }
    }
  }
#pragma unroll
  for (int ni = 0; ni < 4; ++ni)
#pragma unroll
    for (int r = 0; r < 4; ++r) {
      const size_t orow = (size_t)(qb * 64 + w * 16 + lg * 4 + r);
      O[orow * DMODEL + h * HD + ni * 16 + lr] = f2bf(o[ni][r] / lrow[r]);
    }
}

// ---------------- launcher ----------------
extern "C" void kernel_launch(void* const* d_in, const int* in_sizes, int n_in,
                              void* d_out, int out_size, void* d_ws, size_t ws_size,
                              hipStream_t stream) {
  const float* x   = (const float*)d_in[0];
  const float* wq  = (const float*)d_in[1];
  const float* wk  = (const float*)d_in[2];
  const float* wv  = (const float*)d_in[3];
  const float* wo  = (const float*)d_in[4];
  const float* qnw = (const float*)d_in[5];
  const float* knw = (const float*)d_in[6];
  const float* fc  = (const float*)d_in[7];
  const float* fs  = (const float*)d_in[8];
  float* out = (float*)d_out;

  char* ws = (char*)d_ws;
  size_t off = 0;
  auto alloc = [&](size_t bytes) {
    char* p = ws + off;
    off += (bytes + 255) & ~(size_t)255;
    return p;
  };
  u16*   xb   = (u16*)alloc((size_t)S_LEN * DMODEL * 2);
  u16*   wqT  = (u16*)alloc((size_t)DMODEL * DMODEL * 2);
  u16*   wkvT = (u16*)alloc((size_t)512 * DMODEL * 2);
  u16*   woT  = (u16*)alloc((size_t)DMODEL * DMODEL * 2);
  float* KVf  = (float*)alloc((size_t)S_LEN * 512 * 4);
  u16*   Qn   = (u16*)alloc((size_t)S_LEN * DMODEL * 2);
  u16*   Kn   = (u16*)alloc((size_t)S_LEN * 256 * 2);
  u16*   VTb  = (u16*)alloc((size_t)256 * S_LEN * 2);
  u16*   Ob   = (u16*)alloc((size_t)S_LEN * DMODEL * 2);
  float* Qf   = out;  // reuse d_out as fp32 Q scratch (fully overwritten at the end)

  cvt_f32_bf16_v4<<<(S_LEN * DMODEL / 4) / 256, 256, 0, stream>>>(x, xb);
  tconvs<<<(4096 / 32) * (4096 / 32), 256, 0, stream>>>(wq, 4096, wqT, 4096, 4096);
  tconvs<<<(4096 / 32) * (256 / 32), 256, 0, stream>>>(wk, 256, wkvT, 4096, 256);
  tconvs<<<(4096 / 32) * (256 / 32), 256, 0, stream>>>(wv, 256, wkvT + (size_t)256 * 4096, 4096, 256);
  tconvs<<<(4096 / 32) * (4096 / 32), 256, 0, stream>>>(wo, 4096, woT, 4096, 4096);

  gemm_bt<<<(2048 / 128) * (4096 / 128), 256, 0, stream>>>(xb, wqT, Qf, 2048, 4096, 4096);
  gemm_bt<<<(2048 / 128) * (512 / 128), 256, 0, stream>>>(xb, wkvT, KVf, 2048, 512, 4096);

  norm_rope<<<(S_LEN * NH) / 4, 256, 0, stream>>>(Qf, DMODEL, NH, qnw, fc, fs, Qn, DMODEL);
  norm_rope<<<(S_LEN * NKV) / 4, 256, 0, stream>>>(KVf, 512, NKV, knw, fc, fs, Kn, 256);
  // V^T: in = V half of KVf (2048 x 256, row stride 512) -> VT (256 x 2048 bf16)
  tconvs<<<(2048 / 32) * (256 / 32), 256, 0, stream>>>(KVf + 256, 512, VTb, 2048, 256);

  attn_fwd<<<(S_LEN / 64) * NH, 256, 0, stream>>>(Qn, Kn, VTb, Ob);

  gemm_bt<<<(2048 / 128) * (4096 / 128), 256, 0, stream>>>(Ob, woT, out, 2048, 4096, 4096);
}